// Round 9
// baseline (182.687 us; speedup 1.0000x reference)
//
#include <hip/hip_runtime.h>
#include <hip/hip_bf16.h>

// Problem: B=2048, D=512, all fp32.
// q = query@Wq.T+bq ; k,v likewise. attn[b,i,j]=q_i*k_j (rank-1!),
// softmax over j, out[b,i] = sum_j softmax_j(q_i*k_j)*v_j.
//
// Round 9: gemm = R4 verbatim (best measured, ~27 us).
// attn v3: max-subtraction dropped (exp2(c_i) cancels in num/den; args
// bounded by ~+-50, safe in fp32). Exps split across PIPES: 5/8 on the
// trans unit (v_exp_f32, measured ~16 cyc/wave), 3/8 on the VALU via
// poly exp2 (floor+cvt+4xfma+ldexp ~16 cyc) -> both pipes ~balanced,
// target ~10 cyc/exp vs measured 18.

#define B_SZ 2048
#define D_SZ 512

typedef __attribute__((ext_vector_type(2))) float  f32x2;
typedef __attribute__((ext_vector_type(4))) float  f32x4;
typedef __attribute__((ext_vector_type(8))) short  bf16x8;   // MFMA A/B carrier
typedef __attribute__((ext_vector_type(4))) unsigned short u16x4;

__device__ __forceinline__ float exp2_raw(float x) {
#if defined(__has_builtin) && __has_builtin(__builtin_amdgcn_exp2f)
    return __builtin_amdgcn_exp2f(x);
#else
    return exp2f(x);
#endif
}

// VALU-pipe exp2: p(f) = minimax-ish quartic (Taylor@0.5, sqrt2-folded,
// monomial-expanded) on f=fract(x), rel err ~6e-5; scale by 2^floor(x).
__device__ __forceinline__ float exp2_valu(float x) {
    float fl = floorf(x);            // v_floor_f32
    float f  = x - fl;               // v_sub_f32, f in [0,1)
    int   fi = (int)fl;              // v_cvt_i32_f32
    float p = fmaf(f, fmaf(f, fmaf(f, fmaf(f, 0.01360209f, 0.05129093f),
                                   0.24239173f), 0.69259716f), 1.00005555f);
#if defined(__has_builtin) && __has_builtin(__builtin_amdgcn_ldexpf)
    return __builtin_amdgcn_ldexpf(p, fi);   // v_ldexp_f32
#else
    return __uint_as_float(__float_as_uint(p) + ((unsigned)fi << 23));
#endif
}

// Truncation split: hi = top 16 bits of fp32; lo = bf16(trunc) of residual.
// |x - hi - lo| <= 2^-14 |x|
__device__ __forceinline__ void split1(float x, unsigned short& hi, unsigned short& lo) {
    unsigned int u = __float_as_uint(x);
    hi = (unsigned short)(u >> 16);
    float r = x - __uint_as_float(u & 0xFFFF0000u);
    lo = (unsigned short)(__float_as_uint(r) >> 16);
}

__device__ __forceinline__ void split4(const float4& x, u16x4& h, u16x4& l) {
    unsigned short hh, ll;
    split1(x.x, hh, ll); h.x = hh; l.x = ll;
    split1(x.y, hh, ll); h.y = hh; l.y = ll;
    split1(x.z, hh, ll); h.z = hh; l.z = ll;
    split1(x.w, hh, ll); h.w = hh; l.w = ll;
}

// ---------------------------------------------------------------------------
// GEMM (R4 verbatim, ~27 us): Y = X @ W^T + bias via split-bf16 MFMA.
// 64x64 tile, 256 thr (4 waves 2x2), BK=32, register-prefetch pipeline.
// ---------------------------------------------------------------------------
__global__ __launch_bounds__(256) void qkv_gemm_mfma(
    const float* __restrict__ Xq, const float* __restrict__ Xk, const float* __restrict__ Xv,
    const float* __restrict__ Wq, const float* __restrict__ bq,
    const float* __restrict__ Wk, const float* __restrict__ bk,
    const float* __restrict__ Wv, const float* __restrict__ bv,
    float* __restrict__ qkv_out)
{
    const int which = blockIdx.z;
    const float* __restrict__ X    = (which == 0) ? Xq : (which == 1) ? Xk : Xv;
    const float* __restrict__ W    = (which == 0) ? Wq : (which == 1) ? Wk : Wv;
    const float* __restrict__ bias = (which == 0) ? bq : (which == 1) ? bk : bv;
    float* __restrict__ Y = qkv_out + (size_t)which * B_SZ * D_SZ;

    const int t    = threadIdx.x;
    const int lane = t & 63;
    const int wv   = t >> 6;
    const int l15  = lane & 15;
    const int quad = lane >> 4;
    const int wm   = (wv >> 1) * 32;
    const int wn   = (wv & 1) * 32;
    const int m0   = blockIdx.x * 64;
    const int n0   = blockIdx.y * 64;

    __shared__ unsigned short Ahi[64][40], Alo[64][40];
    __shared__ unsigned short Bhi[64][40], Blo[64][40];

    f32x4 acc[2][2] = {{{0.f,0.f,0.f,0.f},{0.f,0.f,0.f,0.f}},
                       {{0.f,0.f,0.f,0.f},{0.f,0.f,0.f,0.f}}};

    const int r0 = t >> 3;
    const int c0 = (t & 7) * 4;
    const int r1 = r0 + 32;

    const float* Xp0 = &X[(size_t)(m0 + r0) * D_SZ + c0];
    const float* Xp1 = &X[(size_t)(m0 + r1) * D_SZ + c0];
    const float* Wp0 = &W[(size_t)(n0 + r0) * D_SZ + c0];
    const float* Wp1 = &W[(size_t)(n0 + r1) * D_SZ + c0];

    float4 xa0 = *(const float4*)(Xp0);
    float4 xa1 = *(const float4*)(Xp1);
    float4 wa0 = *(const float4*)(Wp0);
    float4 wa1 = *(const float4*)(Wp1);

    for (int kk = 0; kk < D_SZ; kk += 32) {
        __syncthreads();
        u16x4 h, l;
        split4(xa0, h, l); *(u16x4*)&Ahi[r0][c0] = h; *(u16x4*)&Alo[r0][c0] = l;
        split4(xa1, h, l); *(u16x4*)&Ahi[r1][c0] = h; *(u16x4*)&Alo[r1][c0] = l;
        split4(wa0, h, l); *(u16x4*)&Bhi[r0][c0] = h; *(u16x4*)&Blo[r0][c0] = l;
        split4(wa1, h, l); *(u16x4*)&Bhi[r1][c0] = h; *(u16x4*)&Blo[r1][c0] = l;
        __syncthreads();

        if (kk + 32 < D_SZ) {
            xa0 = *(const float4*)(Xp0 + kk + 32);
            xa1 = *(const float4*)(Xp1 + kk + 32);
            wa0 = *(const float4*)(Wp0 + kk + 32);
            wa1 = *(const float4*)(Wp1 + kk + 32);
        }

        bf16x8 ah0 = *(const bf16x8*)&Ahi[wm + l15     ][quad * 8];
        bf16x8 ah1 = *(const bf16x8*)&Ahi[wm + 16 + l15][quad * 8];
        bf16x8 al0 = *(const bf16x8*)&Alo[wm + l15     ][quad * 8];
        bf16x8 al1 = *(const bf16x8*)&Alo[wm + 16 + l15][quad * 8];
        bf16x8 bh0 = *(const bf16x8*)&Bhi[wn + l15     ][quad * 8];
        bf16x8 bh1 = *(const bf16x8*)&Bhi[wn + 16 + l15][quad * 8];
        bf16x8 bl0 = *(const bf16x8*)&Blo[wn + l15     ][quad * 8];
        bf16x8 bl1 = *(const bf16x8*)&Blo[wn + 16 + l15][quad * 8];

        acc[0][0] = __builtin_amdgcn_mfma_f32_16x16x32_bf16(ah0, bh0, acc[0][0], 0, 0, 0);
        acc[0][0] = __builtin_amdgcn_mfma_f32_16x16x32_bf16(al0, bh0, acc[0][0], 0, 0, 0);
        acc[0][0] = __builtin_amdgcn_mfma_f32_16x16x32_bf16(ah0, bl0, acc[0][0], 0, 0, 0);
        acc[0][1] = __builtin_amdgcn_mfma_f32_16x16x32_bf16(ah0, bh1, acc[0][1], 0, 0, 0);
        acc[0][1] = __builtin_amdgcn_mfma_f32_16x16x32_bf16(al0, bh1, acc[0][1], 0, 0, 0);
        acc[0][1] = __builtin_amdgcn_mfma_f32_16x16x32_bf16(ah0, bl1, acc[0][1], 0, 0, 0);
        acc[1][0] = __builtin_amdgcn_mfma_f32_16x16x32_bf16(ah1, bh0, acc[1][0], 0, 0, 0);
        acc[1][0] = __builtin_amdgcn_mfma_f32_16x16x32_bf16(al1, bh0, acc[1][0], 0, 0, 0);
        acc[1][0] = __builtin_amdgcn_mfma_f32_16x16x32_bf16(ah1, bl0, acc[1][0], 0, 0, 0);
        acc[1][1] = __builtin_amdgcn_mfma_f32_16x16x32_bf16(ah1, bh1, acc[1][1], 0, 0, 0);
        acc[1][1] = __builtin_amdgcn_mfma_f32_16x16x32_bf16(al1, bh1, acc[1][1], 0, 0, 0);
        acc[1][1] = __builtin_amdgcn_mfma_f32_16x16x32_bf16(ah1, bl1, acc[1][1], 0, 0, 0);
    }

#pragma unroll
    for (int ni = 0; ni < 2; ++ni) {
        const int col = n0 + wn + ni * 16 + l15;
        const float bb = bias[col];
#pragma unroll
        for (int mi = 0; mi < 2; ++mi) {
            const int row = m0 + wm + mi * 16 + quad * 4;
#pragma unroll
            for (int r = 0; r < 4; ++r) {
                Y[(size_t)(row + r) * D_SZ + col] = acc[mi][ni][r] + bb;
            }
        }
    }
}

// ---------------------------------------------------------------------------
// attn v3: out[b,i] = sum_j exp2(q_i*kL_j)*v_j / sum_j exp2(q_i*kL_j).
// No max-subtraction (cancels in the ratio; |arg| <= ~50, fp32-safe).
// One block (256 thr) per b; 2-way j-slicing; 4 i-rows/thread.
// Exps split 5:3 between trans pipe (v_exp_f32) and VALU (poly exp2) so
// the two issue pipes overlap across waves.
// ---------------------------------------------------------------------------
__global__ __launch_bounds__(256) void attn_kernel_v3(
    const float* __restrict__ qkv, float* __restrict__ out)
{
    const int b = blockIdx.x;
    const int t = threadIdx.x;

    const float* __restrict__ q = qkv + (size_t)b * D_SZ;
    const float* __restrict__ k = qkv + (size_t)B_SZ * D_SZ + (size_t)b * D_SZ;
    const float* __restrict__ v = qkv + (size_t)2 * B_SZ * D_SZ + (size_t)b * D_SZ;

    __shared__ float  kv[D_SZ * 2];     // interleaved kL,v (4 KB)
    __shared__ float2 part[2][D_SZ];    // per-j-slice {num,den} partials (8 KB)

    const float L = 1.44269504088896340736f;  // log2(e)

    const int i0 = t & 127;
    const int js = t >> 7;              // 0..1, wave-uniform
    const int jbase = js * 256;

    float qv4[4];
#pragma unroll
    for (int ii = 0; ii < 4; ++ii) qv4[ii] = q[i0 + 128 * ii];

    // stage kv: 2 j's per thread
#pragma unroll
    for (int j = t; j < D_SZ; j += 256) {
        *(float2*)&kv[2 * j] = make_float2(k[j] * L, v[j]);
    }
    __syncthreads();

    f32x2 den[4] = {{0.f,0.f},{0.f,0.f},{0.f,0.f},{0.f,0.f}};
    f32x2 num[4] = {{0.f,0.f},{0.f,0.f},{0.f,0.f},{0.f,0.f}};

#pragma unroll 4
    for (int jc = 0; jc < 256; jc += 2) {
        f32x4 p = *(const f32x4*)&kv[2 * (jbase + jc)];  // kL,v,kL,v
        f32x2 vvp = {p.y, p.w};
        // 5 exps on the trans pipe, 3 on the VALU pipe (balanced issue)
        f32x2 e0 = {exp2_raw (qv4[0] * p.x), exp2_raw (qv4[0] * p.z)};
        f32x2 e1 = {exp2_raw (qv4[1] * p.x), exp2_raw (qv4[1] * p.z)};
        f32x2 e2 = {exp2_raw (qv4[2] * p.x), exp2_valu(qv4[2] * p.z)};
        f32x2 e3 = {exp2_valu(qv4[3] * p.x), exp2_valu(qv4[3] * p.z)};
        den[0] += e0; num[0] += e0 * vvp;
        den[1] += e1; num[1] += e1 * vvp;
        den[2] += e2; num[2] += e2 * vvp;
        den[3] += e3; num[3] += e3 * vvp;
    }

#pragma unroll
    for (int ii = 0; ii < 4; ++ii)
        part[js][i0 + 128 * ii] = make_float2(num[ii].x + num[ii].y,
                                              den[ii].x + den[ii].y);
    __syncthreads();

#pragma unroll
    for (int i = t; i < D_SZ; i += 256) {
        float2 p0 = part[0][i];
        float2 p1 = part[1][i];
        out[(size_t)b * D_SZ + i] = (p0.x + p1.x) / (p0.y + p1.y);
    }
}

extern "C" void kernel_launch(void* const* d_in, const int* in_sizes, int n_in,
                              void* d_out, int out_size, void* d_ws, size_t ws_size,
                              hipStream_t stream) {
    const float* query = (const float*)d_in[0];
    const float* key_  = (const float*)d_in[1];
    const float* value = (const float*)d_in[2];
    const float* Wq    = (const float*)d_in[3];
    const float* bq    = (const float*)d_in[4];
    const float* Wk    = (const float*)d_in[5];
    const float* bk    = (const float*)d_in[6];
    const float* Wv    = (const float*)d_in[7];
    const float* bv    = (const float*)d_in[8];
    float* out = (float*)d_out;

    float* qkv = (float*)d_ws;  // [3][B][D] fp32 = 12.58 MB

    dim3 g1(B_SZ / 64, D_SZ / 64, 3);
    qkv_gemm_mfma<<<g1, 256, 0, stream>>>(query, key_, value, Wq, bq, Wk, bk, Wv, bv, qkv);
    attn_kernel_v3<<<B_SZ, 256, 0, stream>>>(qkv, out);
}